// Round 1
// baseline (155.383 us; speedup 1.0000x reference)
//
#include <hip/hip_runtime.h>

#define NB   32
#define LSEQ 4096
#define DM   512

// db4 decomposition low-pass; DEC_HI[k] = (-1)^(k+1) * DEC_LO[7-k]
__device__ __constant__ float c_DL[8] = {
    -0.010597401784997278f,  0.032883011666982945f,  0.030841381835986965f,
    -0.18703481171888114f,  -0.02798376941698385f,   0.6308807679295904f,
     0.7148465705525415f,    0.23037781330885523f};
__device__ __constant__ float c_DH[8] = {
    -0.23037781330885523f,   0.7148465705525415f,   -0.6308807679295904f,
    -0.02798376941698385f,   0.18703481171888114f,   0.030841381835986965f,
    -0.032883011666982945f, -0.010597401784997278f};

__device__ __forceinline__ int reflect_idx(int i, int N) {
    if (i < 0)  i = -1 - i;
    if (i >= N) i = 2 * N - 1 - i;
    return i;
}

// Forward DWT step: symmetric pad + stride-2 correlation with DL/DH reversed.
// lo[t] = sum_k xp[2t+k] * DL[7-k], xp = sympad(src, padL)
__device__ void fwd_step(const float* __restrict__ src, int N,
                         float* __restrict__ lo, float* __restrict__ hi) {
    int outsize = (N + 7) >> 1;
    int p = 2 * (outsize - 1) - N + 8;
    int padL = p >> 1;
    for (int t = threadIdx.x; t < outsize; t += blockDim.x) {
        int base = 2 * t - padL;
        float aL = 0.f, aH = 0.f;
#pragma unroll
        for (int k = 0; k < 8; ++k) {
            float xv = src[reflect_idx(base + k, N)];
            aL = fmaf(xv, c_DL[7 - k], aL);
            aH = fmaf(xv, c_DH[7 - k], aH);
        }
        lo[t] = aL;
        hi[t] = aH;
    }
}

// Inverse DWT step (one filter path): lhs_dilation=2, pad (1,1), VALID corr.
// y[t] = sum_{j=0..3} c[(t>>1)+j] * F[2j+1-(t&1)], outN = 2n-6 (all in-range)
template <bool HI>
__device__ void inv_step(const float* __restrict__ c, int n, float* __restrict__ y) {
    int outN = 2 * n - 6;
    for (int t = threadIdx.x; t < outN; t += blockDim.x) {
        int base = t >> 1;
        int odd = t & 1;
        float f0 = odd ? (HI ? c_DH[0] : c_DL[0]) : (HI ? c_DH[1] : c_DL[1]);
        float f1 = odd ? (HI ? c_DH[2] : c_DL[2]) : (HI ? c_DH[3] : c_DL[3]);
        float f2 = odd ? (HI ? c_DH[4] : c_DL[4]) : (HI ? c_DH[5] : c_DL[5]);
        float f3 = odd ? (HI ? c_DH[6] : c_DL[6]) : (HI ? c_DH[7] : c_DL[7]);
        float acc = c[base] * f0;
        acc = fmaf(c[base + 1], f1, acc);
        acc = fmaf(c[base + 2], f2, acc);
        acc = fmaf(c[base + 3], f3, acc);
        y[t] = acc;
    }
}

// One block per batch. Projection + 4 fwd levels + 5 IDWT basis chains, all in LDS.
// Writes S[j][b][l] (j in 0..4: lo, h1, h2, h3, h4 matching gate rows 0..4).
__global__ __launch_bounds__(256) void dywpe_dwt_kernel(
    const float* __restrict__ x, const float* __restrict__ proj_w,
    const float* __restrict__ proj_b, float* __restrict__ S) {
    __shared__ float A[4096];
    __shared__ float Bb[2052];
    __shared__ float H1[2051];
    __shared__ float H2[1029];
    __shared__ float H3[518];
    __shared__ float H4[262];
    __shared__ float L4[262];

    int b = blockIdx.x;

    float w[8];
#pragma unroll
    for (int k = 0; k < 8; ++k) w[k] = proj_w[k];
    float pb = proj_b[0];

    const float* xb = x + (size_t)b * LSEQ * 8;
    for (int l = threadIdx.x; l < LSEQ; l += blockDim.x) {
        const float4* xv = (const float4*)(xb + (size_t)l * 8);
        float4 a0 = xv[0], a1 = xv[1];
        float acc = pb;
        acc = fmaf(a0.x, w[0], acc); acc = fmaf(a0.y, w[1], acc);
        acc = fmaf(a0.z, w[2], acc); acc = fmaf(a0.w, w[3], acc);
        acc = fmaf(a1.x, w[4], acc); acc = fmaf(a1.y, w[5], acc);
        acc = fmaf(a1.z, w[6], acc); acc = fmaf(a1.w, w[7], acc);
        A[l] = acc;
    }
    __syncthreads();

    // Forward: 4096 -> 2051 -> 1029 -> 518 -> 262 (ping-pong A/Bb)
    fwd_step(A, 4096, Bb, H1);  __syncthreads();   // lo1 in Bb
    fwd_step(Bb, 2051, A, H2);  __syncthreads();   // lo2 in A
    fwd_step(A, 1029, Bb, H3);  __syncthreads();   // lo3 in Bb
    fwd_step(Bb, 518, L4, H4);  __syncthreads();   // lo4, h4

    const size_t BL = (size_t)NB * LSEQ;
    float* Sb = S + (size_t)b * LSEQ;

    // chain lo -> S[0]: 262 ->518 ->1030(1029) ->2052(2051) ->4096
    inv_step<false>(L4, 262, A);   __syncthreads();
    inv_step<false>(A, 518, Bb);   __syncthreads();
    inv_step<false>(Bb, 1029, A);  __syncthreads();
    inv_step<false>(A, 2051, Sb);  __syncthreads();
    // chain h4 -> S[4]
    inv_step<true >(H4, 262, A);   __syncthreads();
    inv_step<false>(A, 518, Bb);   __syncthreads();
    inv_step<false>(Bb, 1029, A);  __syncthreads();
    inv_step<false>(A, 2051, Sb + 4 * BL); __syncthreads();
    // chain h3 -> S[3]: 518 ->1030(1029) ->2052(2051) ->4096
    inv_step<true >(H3, 518, A);   __syncthreads();
    inv_step<false>(A, 1029, Bb);  __syncthreads();
    inv_step<false>(Bb, 2051, Sb + 3 * BL); __syncthreads();
    // chain h2 -> S[2]: 1029 ->2052(2051) ->4096
    inv_step<true >(H2, 1029, A);  __syncthreads();
    inv_step<false>(A, 2051, Sb + 2 * BL); __syncthreads();
    // chain h1 -> S[1]: 2051 ->4096
    inv_step<true >(H1, 2051, Sb + 1 * BL);
}

// gates[j][c] = sigmoid(se[j]·gw[c] + gb[c]) * tanh(se[j]·gw[512+c] + gb[512+c])
__global__ __launch_bounds__(256) void gates_kernel(
    const float* __restrict__ scale_emb, const float* __restrict__ gate_w,
    const float* __restrict__ gate_b, float* __restrict__ gates) {
    int q = blockIdx.x * blockDim.x + threadIdx.x;
    if (q >= 5 * DM) return;
    int j = q >> 9, c = q & (DM - 1);
    const float4* se = (const float4*)(scale_emb + (size_t)j * DM);
    const float4* g0 = (const float4*)(gate_w + (size_t)c * DM);
    const float4* g1 = (const float4*)(gate_w + (size_t)(DM + c) * DM);
    float ag = 0.f, av = 0.f;
#pragma unroll 4
    for (int i = 0; i < DM / 4; ++i) {
        float4 s = se[i], a = g0[i], bq = g1[i];
        ag = fmaf(s.x, a.x, ag);  ag = fmaf(s.y, a.y, ag);
        ag = fmaf(s.z, a.z, ag);  ag = fmaf(s.w, a.w, ag);
        av = fmaf(s.x, bq.x, av); av = fmaf(s.y, bq.y, av);
        av = fmaf(s.z, bq.z, av); av = fmaf(s.w, bq.w, av);
    }
    ag += gate_b[c];
    av += gate_b[DM + c];
    float sg = 1.f / (1.f + expf(-ag));
    gates[q] = sg * tanhf(av);
}

// pe[b,l,c] = sum_j gates[j][c] * S[j][b*L+l]. Pure write-BW kernel.
__global__ __launch_bounds__(256) void expand_kernel(
    const float* __restrict__ S, const float* __restrict__ gates,
    float* __restrict__ out) {
    __shared__ float gl[5 * DM];
    for (int i = threadIdx.x; i < 5 * DM / 4; i += 256)
        ((float4*)gl)[i] = ((const float4*)gates)[i];
    __syncthreads();

    const size_t BL = (size_t)NB * LSEQ;
    int half = threadIdx.x >> 7;       // 0/1: which of the pair of rows
    int c4 = threadIdx.x & 127;        // float4 index over 512 channels
    float4 g0 = ((const float4*)(gl + 0 * DM))[c4];
    float4 g1 = ((const float4*)(gl + 1 * DM))[c4];
    float4 g2 = ((const float4*)(gl + 2 * DM))[c4];
    float4 g3 = ((const float4*)(gl + 3 * DM))[c4];
    float4 g4 = ((const float4*)(gl + 4 * DM))[c4];

    int rowBase = blockIdx.x * 32;
#pragma unroll 4
    for (int r = 0; r < 16; ++r) {
        int row = rowBase + r * 2 + half;
        float s0 = S[row];
        float s1 = S[BL + row];
        float s2 = S[2 * BL + row];
        float s3 = S[3 * BL + row];
        float s4 = S[4 * BL + row];
        float4 acc;
        acc.x = fmaf(s4, g4.x, fmaf(s3, g3.x, fmaf(s2, g2.x, fmaf(s1, g1.x, s0 * g0.x))));
        acc.y = fmaf(s4, g4.y, fmaf(s3, g3.y, fmaf(s2, g2.y, fmaf(s1, g1.y, s0 * g0.y))));
        acc.z = fmaf(s4, g4.z, fmaf(s3, g3.z, fmaf(s2, g2.z, fmaf(s1, g1.z, s0 * g0.z))));
        acc.w = fmaf(s4, g4.w, fmaf(s3, g3.w, fmaf(s2, g2.w, fmaf(s1, g1.w, s0 * g0.w))));
        ((float4*)out)[(size_t)row * (DM / 4) + c4] = acc;
    }
}

extern "C" void kernel_launch(void* const* d_in, const int* in_sizes, int n_in,
                              void* d_out, int out_size, void* d_ws, size_t ws_size,
                              hipStream_t stream) {
    const float* x         = (const float*)d_in[0];
    const float* proj_w    = (const float*)d_in[1];
    const float* proj_b    = (const float*)d_in[2];
    const float* scale_emb = (const float*)d_in[3];
    const float* gate_w    = (const float*)d_in[4];
    const float* gate_b    = (const float*)d_in[5];
    float* out = (float*)d_out;

    float* S     = (float*)d_ws;                    // 5 * 32 * 4096 floats
    float* gates = S + (size_t)5 * NB * LSEQ;       // 5 * 512 floats

    dywpe_dwt_kernel<<<NB, 256, 0, stream>>>(x, proj_w, proj_b, S);
    gates_kernel<<<10, 256, 0, stream>>>(scale_emb, gate_w, gate_b, gates);
    expand_kernel<<<(NB * LSEQ) / 32, 256, 0, stream>>>(S, gates, out);
}